// Round 3
// baseline (340.664 us; speedup 1.0000x reference)
//
#include <hip/hip_runtime.h>

// MSPushPullLoss R3: register-binned accumulation (no LDS in inner loop).
// B=16, C=16, labels 0..16 (0 = background), seg = b*17+lab, NSEG=272.
// Scales (float4 vecs/batch): 2^18 / 2^16 / 2^14.
// pass1: per-(batch,label) sums + per-(scale,batch,label) counts, 16 reg bins.
// pass2: inline mean, per-(scale,batch,label) pull sums, last-block finalize.

#define NSEG 272
#define M_VAR 0.1f
#define TWO_M_DIST 3.0f
#define GRID_BLOCKS 1008   // scale0: 16*48=768, scale1: 16*12=192, scale2: 16*3=48

__device__ __forceinline__ void gatomic_add(float* p, float v) {
  __hip_atomic_fetch_add(p, v, __ATOMIC_RELAXED, __HIP_MEMORY_SCOPE_AGENT);
}

struct Sel { const float4* f; const int4* g; int vbase, vend, stride, scale, batch; };

__device__ __forceinline__ Sel pick(
    int b, int t,
    const float4* f0, const int4* g0,
    const float4* f1, const int4* g1,
    const float4* f2, const int4* g2) {
  Sel s;
  if (b < 768) {
    int batch = b / 48, sub = b - batch * 48;
    s.f = f0; s.g = g0; s.scale = 0; s.batch = batch;
    s.vbase = batch * 262144 + sub * 256 + t; s.vend = (batch + 1) * 262144; s.stride = 48 * 256;
  } else if (b < 960) {
    int lb = b - 768, batch = lb / 12, sub = lb - batch * 12;
    s.f = f1; s.g = g1; s.scale = 1; s.batch = batch;
    s.vbase = batch * 65536 + sub * 256 + t; s.vend = (batch + 1) * 65536; s.stride = 12 * 256;
  } else {
    int lb = b - 960, batch = lb / 3, sub = lb - batch * 3;
    s.f = f2; s.g = g2; s.scale = 2; s.batch = batch;
    s.vbase = batch * 16384 + sub * 256 + t; s.vend = (batch + 1) * 16384; s.stride = 3 * 256;
  }
  return s;
}

// ---------------- pass 1 ----------------
__global__ __launch_bounds__(256, 4) void pass1_kernel(
    const float4* __restrict__ f0, const int4* __restrict__ g0,
    const float4* __restrict__ f1, const int4* __restrict__ g1,
    const float4* __restrict__ f2, const int4* __restrict__ g2,
    float* __restrict__ tot_sum,   // [NSEG]
    float* __restrict__ cnt)       // [3][NSEG]
{
  const int t = threadIdx.x;
  Sel s = pick(blockIdx.x, t, f0, g0, f1, g1, f2, g2);

  float sum[16]; int cn[16];
  #pragma unroll
  for (int l = 0; l < 16; ++l) { sum[l] = 0.f; cn[l] = 0; }

  auto body = [&](float f, int g) {
    #pragma unroll
    for (int l = 0; l < 16; ++l) {
      bool m = (g == l + 1);
      sum[l] += m ? f : 0.f;   // v_cmp + v_cndmask + v_add
      cn[l]  += m ? 1 : 0;     // reuses vcc (v_addc)
    }
  };

  // one-iteration software prefetch
  int v = s.vbase;
  bool have = v < s.vend;
  float4 fv; int4 gv;
  if (have) { fv = s.f[v]; gv = s.g[v]; }
  while (have) {
    int vn = v + s.stride;
    bool hn = vn < s.vend;
    float4 fn; int4 gn;
    if (hn) { fn = s.f[vn]; gn = s.g[vn]; }
    body(fv.x, gv.x); body(fv.y, gv.y); body(fv.z, gv.z); body(fv.w, gv.w);
    fv = fn; gv = gn; v = vn; have = hn;
  }

  // wave reduce (64 lanes), then cross-wave via LDS
  #pragma unroll
  for (int l = 0; l < 16; ++l) {
    #pragma unroll
    for (int o = 32; o > 0; o >>= 1) {
      sum[l] += __shfl_down(sum[l], o);
      cn[l]  += __shfl_down(cn[l], o);
    }
  }
  __shared__ float rs[4][16];
  __shared__ int   rc[4][16];
  int wave = t >> 6, lane = t & 63;
  if (lane == 0) {
    #pragma unroll
    for (int l = 0; l < 16; ++l) { rs[wave][l] = sum[l]; rc[wave][l] = cn[l]; }
  }
  __syncthreads();
  if (t < 16) {
    float sv = rs[0][t] + rs[1][t] + rs[2][t] + rs[3][t];
    int   cv = rc[0][t] + rc[1][t] + rc[2][t] + rc[3][t];
    if (cv != 0) {
      gatomic_add(&tot_sum[s.batch * 17 + t + 1], sv);
      gatomic_add(&cnt[s.scale * NSEG + s.batch * 17 + t + 1], (float)cv);
    }
  }
}

// ---------------- pass 2 (+ inline mean, + last-block finalize) ----------------
__global__ __launch_bounds__(256, 4) void pass2_kernel(
    const float4* __restrict__ f0, const int4* __restrict__ g0,
    const float4* __restrict__ f1, const int4* __restrict__ g1,
    const float4* __restrict__ f2, const int4* __restrict__ g2,
    const float* __restrict__ tot_sum,  // [NSEG]
    const float* __restrict__ cnt,      // [3][NSEG]
    float* __restrict__ pull,           // [3][NSEG]
    int* __restrict__ counter,
    float* __restrict__ out)
{
  __shared__ float s_mean[17];
  const int t = threadIdx.x;
  Sel s = pick(blockIdx.x, t, f0, g0, f1, g1, f2, g2);

  if (t < 17) {
    int seg = s.batch * 17 + t;
    float c = cnt[seg] + cnt[NSEG + seg] + cnt[2 * NSEG + seg];
    s_mean[t] = tot_sum[seg] / fmaxf(c, 1.f);
  }
  __syncthreads();

  float acc[16];
  #pragma unroll
  for (int l = 0; l < 16; ++l) acc[l] = 0.f;

  auto body = [&](float f, int g) {
    unsigned gi = (unsigned)g; gi = gi > 16u ? 16u : gi;
    float d = fmaxf(fabsf(f - s_mean[gi]) - M_VAR, 0.f);
    float d2 = d * d;
    #pragma unroll
    for (int l = 0; l < 16; ++l) acc[l] += (g == l + 1) ? d2 : 0.f;
  };

  int v = s.vbase;
  bool have = v < s.vend;
  float4 fv; int4 gv;
  if (have) { fv = s.f[v]; gv = s.g[v]; }
  while (have) {
    int vn = v + s.stride;
    bool hn = vn < s.vend;
    float4 fn; int4 gn;
    if (hn) { fn = s.f[vn]; gn = s.g[vn]; }
    body(fv.x, gv.x); body(fv.y, gv.y); body(fv.z, gv.z); body(fv.w, gv.w);
    fv = fn; gv = gn; v = vn; have = hn;
  }

  #pragma unroll
  for (int l = 0; l < 16; ++l) {
    #pragma unroll
    for (int o = 32; o > 0; o >>= 1) acc[l] += __shfl_down(acc[l], o);
  }
  __shared__ float rs[4][16];
  int wave = t >> 6, lane = t & 63;
  if (lane == 0) {
    #pragma unroll
    for (int l = 0; l < 16; ++l) rs[wave][l] = acc[l];
  }
  __syncthreads();
  if (t < 16) {
    float sv = rs[0][t] + rs[1][t] + rs[2][t] + rs[3][t];
    if (sv != 0.f) gatomic_add(&pull[s.scale * NSEG + s.batch * 17 + t + 1], sv);
  }

  // ---- completion ticket; last block finalizes ----
  __threadfence();
  __shared__ int is_last;
  if (t == 0) {
    int ticket = __hip_atomic_fetch_add(counter, 1, __ATOMIC_ACQ_REL, __HIP_MEMORY_SCOPE_AGENT);
    is_last = (ticket == GRID_BLOCKS - 1) ? 1 : 0;
  }
  __syncthreads();
  if (!is_last) return;
  __threadfence();

  __shared__ float fz_mean[NSEG];
  __shared__ unsigned char fz_pres[NSEG];
  for (int i = t; i < NSEG; i += 256) {
    float c = cnt[i] + cnt[NSEG + i] + cnt[2 * NSEG + i];
    fz_pres[i] = (c > 0.f) ? 1 : 0;
    fz_mean[i] = tot_sum[i] / fmaxf(c, 1.f);
  }
  __syncthreads();

  float pull_v = 0.f, pull_n = 0.f, push_v = 0.f, push_n = 0.f;

  for (int i = t; i < NSEG; i += 256) {
    int lab = i - (i / 17) * 17;
    if (lab >= 1 && fz_pres[i]) {
      float ps = 0.f;
      float c0 = cnt[i];            if (c0 > 0.f) ps += pull[i] / c0;
      float c1 = cnt[NSEG + i];     if (c1 > 0.f) ps += pull[NSEG + i] / c1;
      float c2 = cnt[2 * NSEG + i]; if (c2 > 0.f) ps += pull[2 * NSEG + i] / c2;
      pull_v += ps;
      pull_n += 1.f;
    }
  }
  {
    int b = t >> 4, ii = t & 15;
    int si = b * 17 + ii + 1;
    if (fz_pres[si]) {
      float mi = fz_mean[si];
      for (int j = 0; j < 16; ++j) {
        if (j == ii) continue;
        int sj = b * 17 + j + 1;
        if (fz_pres[sj]) {
          float d = fmaxf(TWO_M_DIST - fabsf(mi - fz_mean[sj]), 0.f);
          push_v += d * d;
          push_n += 1.f;
        }
      }
    }
  }

  #pragma unroll
  for (int o = 32; o > 0; o >>= 1) {
    pull_v += __shfl_down(pull_v, o);
    pull_n += __shfl_down(pull_n, o);
    push_v += __shfl_down(push_v, o);
    push_n += __shfl_down(push_n, o);
  }
  __shared__ float r[4][4];
  if (lane == 0) { r[wave][0] = pull_v; r[wave][1] = pull_n; r[wave][2] = push_v; r[wave][3] = push_n; }
  __syncthreads();
  if (t == 0) {
    float PV = 0, PN = 0, SV = 0, SN = 0;
    for (int w = 0; w < 4; ++w) { PV += r[w][0]; PN += r[w][1]; SV += r[w][2]; SN += r[w][3]; }
    out[0] = PV / fmaxf(PN, 1.f) + SV / fmaxf(SN, 1.f);
  }
}

extern "C" void kernel_launch(void* const* d_in, const int* in_sizes, int n_in,
                              void* d_out, int out_size, void* d_ws, size_t ws_size,
                              hipStream_t stream) {
  // setup_inputs() dict order: featmap0, gt0, featmap1, gt1, featmap2, gt2
  const float4* f0 = (const float4*)d_in[0];
  const int4*   g0 = (const int4*)  d_in[1];
  const float4* f1 = (const float4*)d_in[2];
  const int4*   g1 = (const int4*)  d_in[3];
  const float4* f2 = (const float4*)d_in[4];
  const int4*   g2 = (const int4*)  d_in[5];

  float* ws      = (float*)d_ws;
  float* tot_sum = ws;                 // [NSEG]
  float* cnt     = ws + NSEG;          // [3][NSEG]
  float* pull    = ws + 4 * NSEG;      // [3][NSEG]
  int*   counter = (int*)(ws + 7 * NSEG);

  hipMemsetAsync(d_ws, 0, (7 * NSEG + 1) * sizeof(float), stream);
  pass1_kernel<<<GRID_BLOCKS, 256, 0, stream>>>(f0, g0, f1, g1, f2, g2, tot_sum, cnt);
  pass2_kernel<<<GRID_BLOCKS, 256, 0, stream>>>(f0, g0, f1, g1, f2, g2, tot_sum, cnt,
                                                pull, counter, (float*)d_out);
}